// Round 2
// baseline (5545.449 us; speedup 1.0000x reference)
//
#include <hip/hip_runtime.h>
#include <hip/hip_bf16.h>

#define B_ 128
#define T_ 1024
#define E_ 32
#define H_ 100
#define C_ 20
#define M_ (B_*T_)   // 131072

// ---------------- embedding lookup ----------------
__global__ void embed_k(const int* __restrict__ tok, const float* __restrict__ emb,
                        float* __restrict__ x0) {
  int idx = blockIdx.x * 256 + threadIdx.x;   // over M_*E_ = 4194304
  int bt = idx >> 5;
  int e  = idx & 31;
  x0[idx] = emb[tok[bt] * E_ + e];
}

// ---------------- generic fp32 GEMM: C[M,N] = A[M,K] @ W[N,K]^T + b1 + b2 ----
// BM=64, BN=64, BK=8, 256 threads, 4x4 microtile
__global__ __launch_bounds__(256) void gemm_nt(
    const float* __restrict__ A, const float* __restrict__ W,
    const float* __restrict__ b1, const float* __restrict__ b2,
    float* __restrict__ C, int K, int N, int ldc)
{
  const int BK = 8;
  __shared__ __align__(16) float As[BK][68];
  __shared__ __align__(16) float Ws[BK][68];
  int tid = threadIdx.x;
  size_t m0 = (size_t)blockIdx.x * 64;
  int n0 = blockIdx.y * 64;
  int ty = tid >> 4, tx = tid & 15;
  int lm = tid >> 2;          // 0..63
  int lk = (tid & 3) * 2;     // 0,2,4,6
  float acc[4][4] = {{0.f}};
  const float* Ap = A + (m0 + (size_t)lm) * K + lk;
  bool wok = (n0 + lm) < N;
  const float* Wp = wok ? (W + (size_t)(n0 + lm) * K + lk) : W;
  for (int k0 = 0; k0 < K; k0 += BK) {
    float2 av = *(const float2*)(Ap + k0);
    float2 wv = wok ? *(const float2*)(Wp + k0) : make_float2(0.f, 0.f);
    As[lk][lm] = av.x; As[lk + 1][lm] = av.y;
    Ws[lk][lm] = wv.x; Ws[lk + 1][lm] = wv.y;
    __syncthreads();
    #pragma unroll
    for (int k = 0; k < BK; ++k) {
      float4 a4 = *(const float4*)&As[k][ty * 4];
      float4 w4 = *(const float4*)&Ws[k][tx * 4];
      float ar[4] = {a4.x, a4.y, a4.z, a4.w};
      float wr[4] = {w4.x, w4.y, w4.z, w4.w};
      #pragma unroll
      for (int i = 0; i < 4; ++i)
        #pragma unroll
        for (int j = 0; j < 4; ++j)
          acc[i][j] = fmaf(ar[i], wr[j], acc[i][j]);
    }
    __syncthreads();
  }
  #pragma unroll
  for (int i = 0; i < 4; ++i) {
    size_t row = m0 + ty * 4 + i;
    #pragma unroll
    for (int j = 0; j < 4; ++j) {
      int col = n0 + tx * 4 + j;
      if (col < N) {
        float bv = (b1 ? b1[col] : 0.f) + (b2 ? b2[col] : 0.f);
        C[row * (size_t)ldc + col] = acc[i][j] + bv;
      }
    }
  }
}

// ---------------- LSTM scan (one WG per (batch, direction)) -----------------
// xp: [2][B][T][400] precomputed input projections (+both biases)
// 512 threads: thread r<400 owns W_hh row r in registers (25 float4 = 100 VGPR)
// -> no spill (was: 2 rows/thread = 200 VGPR demand -> scratch spill, 1100us)
__global__ __launch_bounds__(512, 2) void lstm_scan(
    const float* __restrict__ xp,
    const float* __restrict__ WhhF, const float* __restrict__ WhhR,
    const float* __restrict__ h0, const float* __restrict__ c0, // [4][B][H]
    const int* __restrict__ seqlen,   // null => no mask
    float* __restrict__ outbuf,       // [B][T][200], dir*100 offset
    int layer)
{
  int wg = blockIdx.x; int dir = wg & 1; int b = wg >> 1;
  int tid = threadIdx.x;
  const float* Whh = dir ? WhhR : WhhF;
  const float* xpp = xp + ((size_t)dir * B_ + b) * T_ * 400;
  const float* h0p = h0 + ((size_t)(2 * layer + dir) * B_ + b) * H_;
  const float* c0p = c0 + ((size_t)(2 * layer + dir) * B_ + b) * H_;
  __shared__ __align__(16) float hsh[104];
  __shared__ __align__(16) float gsh[400];
  float4 w[25];
  if (tid < 400) {
    const float4* p = (const float4*)(Whh + (size_t)tid * H_);
    #pragma unroll
    for (int j = 0; j < 25; ++j) w[j] = p[j];
  }
  if (tid < H_) hsh[tid] = h0p[tid];
  float c = (tid < H_) ? c0p[tid] : 0.f;
  int sl = seqlen ? seqlen[b] : T_;
  __syncthreads();
  int tstep = dir ? -1 : 1;
  int t0 = dir ? (T_ - 1) : 0;
  float xc = 0.f, xn = 0.f;
  if (tid < 400) {
    xc = xpp[(size_t)t0 * 400 + tid];
    xn = xpp[(size_t)(t0 + tstep) * 400 + tid];
  }
  for (int tt = 0; tt < T_; ++tt) {
    int t = t0 + tstep * tt;
    float xn2 = 0.f;
    if (tid < 400 && tt + 2 < T_)
      xn2 = xpp[(size_t)(t + 2 * tstep) * 400 + tid];
    if (tid < 400) {
      // two independent accumulator chains (even/odd j) to hide FMA latency
      float a0 = xc, a1 = 0.f;
      #pragma unroll
      for (int j = 0; j < 25; j += 2) {
        float4 hv = *(const float4*)&hsh[4 * j];
        a0 = fmaf(w[j].x, hv.x, a0); a0 = fmaf(w[j].y, hv.y, a0);
        a0 = fmaf(w[j].z, hv.z, a0); a0 = fmaf(w[j].w, hv.w, a0);
      }
      #pragma unroll
      for (int j = 1; j < 25; j += 2) {
        float4 hv = *(const float4*)&hsh[4 * j];
        a1 = fmaf(w[j].x, hv.x, a1); a1 = fmaf(w[j].y, hv.y, a1);
        a1 = fmaf(w[j].z, hv.z, a1); a1 = fmaf(w[j].w, hv.w, a1);
      }
      gsh[tid] = a0 + a1;
    }
    __syncthreads();
    if (tid < H_) {
      float gi = gsh[tid], gf = gsh[H_ + tid], gg = gsh[2 * H_ + tid], go = gsh[3 * H_ + tid];
      float si = 1.f / (1.f + __expf(-gi));
      float sf = 1.f / (1.f + __expf(-gf));
      float so = 1.f / (1.f + __expf(-go));
      float tg = 1.f - 2.f / (1.f + __expf(2.f * gg));
      c = fmaf(sf, c, si * tg);
      float tc = 1.f - 2.f / (1.f + __expf(2.f * c));
      float h = so * tc;
      hsh[tid] = h;
      outbuf[((size_t)b * T_ + t) * 200 + dir * H_ + tid] = (t < sl) ? h : 0.f;
    }
    __syncthreads();
    xc = xn; xn = xn2;
  }
}

// ---------------- CRF alpha (wg<B) + beta (wg>=B), one wave per batch -------
__global__ __launch_bounds__(64) void crf_k(
    const float* __restrict__ f, const float* __restrict__ g,
    float* __restrict__ alpha, float* __restrict__ beta)
{
  int wg = blockIdx.x;
  int lane = threadIdx.x;
  float gv[20], gn1[20], gn2[20], sv[20];
  #pragma unroll
  for (int q = 0; q < 20; ++q) { gv[q] = 0.f; gn1[q] = 0.f; gn2[q] = 0.f; }
  if (wg < B_) {
    int b = wg;
    const float* fp = f + (size_t)b * T_ * C_;
    const float* gp = g + (size_t)b * T_ * C_ * C_;
    float* ap = alpha + (size_t)b * T_ * C_;
    float a = 0.f;
    if (lane < C_) { a = fp[lane]; ap[lane] = a; }
    if (lane < C_) {
      #pragma unroll
      for (int q = 0; q < 20; ++q) gv[q] = gp[(size_t)1 * 400 + q * 20 + lane];
      #pragma unroll
      for (int q = 0; q < 20; ++q) gn1[q] = gp[(size_t)2 * 400 + q * 20 + lane];
    }
    for (int t = 1; t < T_; ++t) {
      if (t + 2 < T_ && lane < C_) {
        #pragma unroll
        for (int q = 0; q < 20; ++q) gn2[q] = gp[(size_t)(t + 2) * 400 + q * 20 + lane];
      }
      float ft = (lane < C_) ? fp[t * C_ + lane] : 0.f;
      float m = -3.0e38f;
      #pragma unroll
      for (int q = 0; q < 20; ++q) {
        float s = __shfl(a, q) + gv[q];
        sv[q] = s; m = fmaxf(m, s);
      }
      float sum = 0.f;
      #pragma unroll
      for (int q = 0; q < 20; ++q) sum += __expf(sv[q] - m);
      a = ft + m + __logf(sum);
      if (lane < C_) ap[(size_t)t * C_ + lane] = a;
      #pragma unroll
      for (int q = 0; q < 20; ++q) { gv[q] = gn1[q]; gn1[q] = gn2[q]; }
    }
  } else {
    int b = wg - B_;
    const float* fp = f + (size_t)b * T_ * C_;
    const float* gp = g + (size_t)b * T_ * C_ * C_;
    float* bp = beta + (size_t)b * T_ * C_;
    float bv = 0.f;
    if (lane < C_) bp[(size_t)(T_ - 1) * C_ + lane] = 0.f;
    if (lane < C_) {
      #pragma unroll
      for (int q = 0; q < 20; ++q) gv[q] = gp[(size_t)(T_ - 1) * 400 + lane * 20 + q];
      #pragma unroll
      for (int q = 0; q < 20; ++q) gn1[q] = gp[(size_t)(T_ - 2) * 400 + lane * 20 + q];
    }
    for (int t = T_ - 2; t >= 0; --t) {
      if (t >= 2 && lane < C_) {
        #pragma unroll
        for (int q = 0; q < 20; ++q) gn2[q] = gp[(size_t)(t - 1) * 400 + lane * 20 + q];
      }
      float w = ((lane < C_) ? fp[(t + 1) * C_ + lane] : 0.f) + bv;
      float m = -3.0e38f;
      #pragma unroll
      for (int q = 0; q < 20; ++q) {
        float s = gv[q] + __shfl(w, q);
        sv[q] = s; m = fmaxf(m, s);
      }
      float sum = 0.f;
      #pragma unroll
      for (int q = 0; q < 20; ++q) sum += __expf(sv[q] - m);
      bv = m + __logf(sum);
      if (lane < C_) bp[(size_t)t * C_ + lane] = bv;
      #pragma unroll
      for (int q = 0; q < 20; ++q) { gv[q] = gn1[q]; gn1[q] = gn2[q]; }
    }
  }
}

// ---------------- logZ per batch ----------------
__global__ void logz_k(const float* __restrict__ alpha, float* __restrict__ lz) {
  int b = blockIdx.x; int lane = threadIdx.x;
  float a = (lane < C_) ? alpha[((size_t)b * T_ + (T_ - 1)) * C_ + lane] : -3.0e38f;
  float m = a;
  #pragma unroll
  for (int o = 32; o > 0; o >>= 1) m = fmaxf(m, __shfl_xor(m, o));
  float e = (lane < C_) ? __expf(a - m) : 0.f;
  #pragma unroll
  for (int o = 32; o > 0; o >>= 1) e += __shfl_xor(e, o);
  if (lane == 0) lz[b] = m + __logf(e);
}

// ---------------- marginals = exp(alpha+beta-logZ) ----------------
__global__ void marg_k(const float* __restrict__ alpha, const float* __restrict__ beta,
                       const float* __restrict__ lz, float* __restrict__ out0) {
  size_t idx = (size_t)blockIdx.x * 256 + threadIdx.x;
  int b = (int)(idx / (T_ * C_));
  out0[idx] = __expf(alpha[idx] + beta[idx] - lz[b]);
}

extern "C" void kernel_launch(void* const* d_in, const int* in_sizes, int n_in,
                              void* d_out, int out_size, void* d_ws, size_t ws_size,
                              hipStream_t stream) {
  const int*   tok   = (const int*)d_in[0];
  const int*   seq   = (const int*)d_in[1];
  const float* emb   = (const float*)d_in[2];
  const float* Wih0  = (const float*)d_in[3];
  const float* Whh0  = (const float*)d_in[4];
  const float* bih0  = (const float*)d_in[5];
  const float* bhh0  = (const float*)d_in[6];
  const float* Wih0r = (const float*)d_in[7];
  const float* Whh0r = (const float*)d_in[8];
  const float* bih0r = (const float*)d_in[9];
  const float* bhh0r = (const float*)d_in[10];
  const float* Wih1  = (const float*)d_in[11];
  const float* Whh1  = (const float*)d_in[12];
  const float* bih1  = (const float*)d_in[13];
  const float* bhh1  = (const float*)d_in[14];
  const float* Wih1r = (const float*)d_in[15];
  const float* Whh1r = (const float*)d_in[16];
  const float* bih1r = (const float*)d_in[17];
  const float* bhh1r = (const float*)d_in[18];
  const float* fW    = (const float*)d_in[19];
  const float* fb    = (const float*)d_in[20];
  const float* gW    = (const float*)d_in[21];
  const float* gb    = (const float*)d_in[22];
  const float* h0    = (const float*)d_in[23];
  const float* c0    = (const float*)d_in[24];

  float* ws = (float*)d_ws;
  float* x0 = ws;                         // 4,194,304 floats
  float* xp = ws + 4194304;               // 2*B*T*400 = 104,857,600 floats
  float* x1 = ws + 109051904;             // 26,214,400 floats (layer0 out; reused as layer1 out)
  float* lz = ws + 135266304;             // 128 floats

  float* out   = (float*)d_out;
  float* f_out = out + 2621440;
  float* g_out = out + 5242880;
  float* a_out = out + 57671680;
  float* b_out = out + 60293120;

  embed_k<<<16384, 256, 0, stream>>>(tok, emb, x0);

  dim3 g400(2048, 7), g20(2048, 1);
  // layer 0 input projections (K=32)
  gemm_nt<<<g400, 256, 0, stream>>>(x0, Wih0,  bih0,  bhh0,  xp,                    32, 400, 400);
  gemm_nt<<<g400, 256, 0, stream>>>(x0, Wih0r, bih0r, bhh0r, xp + (size_t)52428800, 32, 400, 400);
  lstm_scan<<<256, 512, 0, stream>>>(xp, Whh0, Whh0r, h0, c0, nullptr, x1, 0);
  // layer 1 input projections (K=200)
  gemm_nt<<<g400, 256, 0, stream>>>(x1, Wih1,  bih1,  bhh1,  xp,                    200, 400, 400);
  gemm_nt<<<g400, 256, 0, stream>>>(x1, Wih1r, bih1r, bhh1r, xp + (size_t)52428800, 200, 400, 400);
  lstm_scan<<<256, 512, 0, stream>>>(xp, Whh1, Whh1r, h0, c0, seq, x1, 1);  // x1 reused as h
  // emissions + transitions
  gemm_nt<<<g20,  256, 0, stream>>>(x1, fW, fb, nullptr, f_out, 200, 20,  20);
  gemm_nt<<<g400, 256, 0, stream>>>(x1, gW, gb, nullptr, g_out, 200, 400, 400);
  // CRF forward/backward (alpha: blocks 0..127, beta: 128..255)
  crf_k<<<256, 64, 0, stream>>>(f_out, g_out, a_out, b_out);
  logz_k<<<128, 64, 0, stream>>>(a_out, lz);
  marg_k<<<10240, 256, 0, stream>>>(a_out, b_out, lz, out);
}

// Round 3
// 4450.118 us; speedup vs baseline: 1.2461x; 1.2461x over previous
//
#include <hip/hip_runtime.h>
#include <hip/hip_bf16.h>

#define B_ 128
#define T_ 1024
#define E_ 32
#define H_ 100
#define C_ 20
#define M_ (B_*T_)   // 131072

// ---------------- embedding lookup ----------------
__global__ void embed_k(const int* __restrict__ tok, const float* __restrict__ emb,
                        float* __restrict__ x0) {
  int idx = blockIdx.x * 256 + threadIdx.x;   // over M_*E_ = 4194304
  int bt = idx >> 5;
  int e  = idx & 31;
  x0[idx] = emb[tok[bt] * E_ + e];
}

// ---------------- generic fp32 GEMM: C[M,N] = A[M,K] @ W[N,K]^T + b1 + b2 ----
// BM=64, BN=64, BK=8, 256 threads, 4x4 microtile
__global__ __launch_bounds__(256) void gemm_nt(
    const float* __restrict__ A, const float* __restrict__ W,
    const float* __restrict__ b1, const float* __restrict__ b2,
    float* __restrict__ C, int K, int N, int ldc)
{
  const int BK = 8;
  __shared__ __align__(16) float As[BK][68];
  __shared__ __align__(16) float Ws[BK][68];
  int tid = threadIdx.x;
  size_t m0 = (size_t)blockIdx.x * 64;
  int n0 = blockIdx.y * 64;
  int ty = tid >> 4, tx = tid & 15;
  int lm = tid >> 2;          // 0..63
  int lk = (tid & 3) * 2;     // 0,2,4,6
  float acc[4][4] = {{0.f}};
  const float* Ap = A + (m0 + (size_t)lm) * K + lk;
  bool wok = (n0 + lm) < N;
  const float* Wp = wok ? (W + (size_t)(n0 + lm) * K + lk) : W;
  for (int k0 = 0; k0 < K; k0 += BK) {
    float2 av = *(const float2*)(Ap + k0);
    float2 wv = wok ? *(const float2*)(Wp + k0) : make_float2(0.f, 0.f);
    As[lk][lm] = av.x; As[lk + 1][lm] = av.y;
    Ws[lk][lm] = wv.x; Ws[lk + 1][lm] = wv.y;
    __syncthreads();
    #pragma unroll
    for (int k = 0; k < BK; ++k) {
      float4 a4 = *(const float4*)&As[k][ty * 4];
      float4 w4 = *(const float4*)&Ws[k][tx * 4];
      float ar[4] = {a4.x, a4.y, a4.z, a4.w};
      float wr[4] = {w4.x, w4.y, w4.z, w4.w};
      #pragma unroll
      for (int i = 0; i < 4; ++i)
        #pragma unroll
        for (int j = 0; j < 4; ++j)
          acc[i][j] = fmaf(ar[i], wr[j], acc[i][j]);
    }
    __syncthreads();
  }
  #pragma unroll
  for (int i = 0; i < 4; ++i) {
    size_t row = m0 + ty * 4 + i;
    #pragma unroll
    for (int j = 0; j < 4; ++j) {
      int col = n0 + tx * 4 + j;
      if (col < N) {
        float bv = (b1 ? b1[col] : 0.f) + (b2 ? b2[col] : 0.f);
        C[row * (size_t)ldc + col] = acc[i][j] + bv;
      }
    }
  }
}

// ---------------- LSTM scan (one WG per (batch, direction)) -----------------
// xp: [2][B][T][400] precomputed input projections (+both biases)
// 1024 threads: thread pair (2r, 2r+1) owns W_hh row r split 52/48 along k.
// Per-thread weight footprint = 13 float4 = 52 VGPR -> stays register-resident
// (rounds 1/2: 100-200 float demand -> LLVM remat'd the loads from L2 every
// step, 42GB of L2 traffic, 1.1-1.7ms). Halves combined via shfl_xor(1).
__global__
__attribute__((amdgpu_flat_work_group_size(1024, 1024), amdgpu_waves_per_eu(4, 4)))
void lstm_scan(
    const float* __restrict__ xp,
    const float* __restrict__ WhhF, const float* __restrict__ WhhR,
    const float* __restrict__ h0, const float* __restrict__ c0, // [4][B][H]
    const int* __restrict__ seqlen,   // null => no mask
    float* __restrict__ outbuf,       // [B][T][200], dir*100 offset
    int layer)
{
  int wg = blockIdx.x; int dir = wg & 1; int b = wg >> 1;
  int tid = threadIdx.x;
  const float* Whh = dir ? WhhR : WhhF;
  const float* xpp = xp + ((size_t)dir * B_ + b) * T_ * 400;
  const float* h0p = h0 + ((size_t)(2 * layer + dir) * B_ + b) * H_;
  const float* c0p = c0 + ((size_t)(2 * layer + dir) * B_ + b) * H_;
  __shared__ __align__(16) float hsh[104];
  __shared__ __align__(16) float gsh[400];
  int r = tid >> 1;          // gate row 0..511 (active < 400)
  int half = tid & 1;        // k-half: 0 -> [0,52), 1 -> [52,100)
  bool act = (tid < 800);
  int kbase = half ? 52 : 0;
  float4 w[13];
  if (act) {
    const float4* p = (const float4*)(Whh + (size_t)r * H_ + kbase);
    #pragma unroll
    for (int j = 0; j < 12; ++j) w[j] = p[j];
    w[12] = half ? make_float4(0.f, 0.f, 0.f, 0.f) : p[12];
  }
  if (tid < H_) hsh[tid] = h0p[tid];
  float c = (tid < H_) ? c0p[tid] : 0.f;
  int sl = seqlen ? seqlen[b] : T_;
  __syncthreads();
  int tstep = dir ? -1 : 1;
  int t0 = dir ? (T_ - 1) : 0;
  float xc = 0.f, xn = 0.f;
  if (act) {
    xc = xpp[(size_t)t0 * 400 + r];
    xn = xpp[(size_t)(t0 + tstep) * 400 + r];
  }
  for (int tt = 0; tt < T_; ++tt) {
    int t = t0 + tstep * tt;
    float xn2 = 0.f;
    if (act && tt + 2 < T_)
      xn2 = xpp[(size_t)(t + 2 * tstep) * 400 + r];
    if (act) {
      // two independent chains to hide FMA latency
      float s0 = half ? 0.f : xc;
      float s1 = 0.f;
      #pragma unroll
      for (int j = 0; j < 13; j += 2) {
        float4 hv = *(const float4*)&hsh[kbase + 4 * j];
        s0 = fmaf(w[j].x, hv.x, s0); s0 = fmaf(w[j].y, hv.y, s0);
        s0 = fmaf(w[j].z, hv.z, s0); s0 = fmaf(w[j].w, hv.w, s0);
      }
      #pragma unroll
      for (int j = 1; j < 13; j += 2) {
        float4 hv = *(const float4*)&hsh[kbase + 4 * j];
        s1 = fmaf(w[j].x, hv.x, s1); s1 = fmaf(w[j].y, hv.y, s1);
        s1 = fmaf(w[j].z, hv.z, s1); s1 = fmaf(w[j].w, hv.w, s1);
      }
      float s = s0 + s1;
      s += __shfl_xor(s, 1);   // combine the two k-halves (adjacent lanes)
      if (!half) gsh[r] = s;
    }
    __syncthreads();
    if (tid < H_) {
      float gi = gsh[tid], gf = gsh[H_ + tid], gg = gsh[2 * H_ + tid], go = gsh[3 * H_ + tid];
      float si = 1.f / (1.f + __expf(-gi));
      float sf = 1.f / (1.f + __expf(-gf));
      float so = 1.f / (1.f + __expf(-go));
      float tg = 1.f - 2.f / (1.f + __expf(2.f * gg));
      c = fmaf(sf, c, si * tg);
      float tc = 1.f - 2.f / (1.f + __expf(2.f * c));
      float h = so * tc;
      hsh[tid] = h;
      outbuf[((size_t)b * T_ + t) * 200 + dir * H_ + tid] = (t < sl) ? h : 0.f;
    }
    __syncthreads();
    xc = xn; xn = xn2;
  }
}

// ---------------- CRF alpha (wg<B) + beta (wg>=B), one wave per batch -------
__global__ __launch_bounds__(64) void crf_k(
    const float* __restrict__ f, const float* __restrict__ g,
    float* __restrict__ alpha, float* __restrict__ beta)
{
  int wg = blockIdx.x;
  int lane = threadIdx.x;
  float gv[20], gn1[20], gn2[20], sv[20];
  #pragma unroll
  for (int q = 0; q < 20; ++q) { gv[q] = 0.f; gn1[q] = 0.f; gn2[q] = 0.f; }
  if (wg < B_) {
    int b = wg;
    const float* fp = f + (size_t)b * T_ * C_;
    const float* gp = g + (size_t)b * T_ * C_ * C_;
    float* ap = alpha + (size_t)b * T_ * C_;
    float a = 0.f;
    if (lane < C_) { a = fp[lane]; ap[lane] = a; }
    if (lane < C_) {
      #pragma unroll
      for (int q = 0; q < 20; ++q) gv[q] = gp[(size_t)1 * 400 + q * 20 + lane];
      #pragma unroll
      for (int q = 0; q < 20; ++q) gn1[q] = gp[(size_t)2 * 400 + q * 20 + lane];
    }
    for (int t = 1; t < T_; ++t) {
      if (t + 2 < T_ && lane < C_) {
        #pragma unroll
        for (int q = 0; q < 20; ++q) gn2[q] = gp[(size_t)(t + 2) * 400 + q * 20 + lane];
      }
      float ft = (lane < C_) ? fp[t * C_ + lane] : 0.f;
      float m = -3.0e38f;
      #pragma unroll
      for (int q = 0; q < 20; ++q) {
        float s = __shfl(a, q) + gv[q];
        sv[q] = s; m = fmaxf(m, s);
      }
      float sum = 0.f;
      #pragma unroll
      for (int q = 0; q < 20; ++q) sum += __expf(sv[q] - m);
      a = ft + m + __logf(sum);
      if (lane < C_) ap[(size_t)t * C_ + lane] = a;
      #pragma unroll
      for (int q = 0; q < 20; ++q) { gv[q] = gn1[q]; gn1[q] = gn2[q]; }
    }
  } else {
    int b = wg - B_;
    const float* fp = f + (size_t)b * T_ * C_;
    const float* gp = g + (size_t)b * T_ * C_ * C_;
    float* bp = beta + (size_t)b * T_ * C_;
    float bv = 0.f;
    if (lane < C_) bp[(size_t)(T_ - 1) * C_ + lane] = 0.f;
    if (lane < C_) {
      #pragma unroll
      for (int q = 0; q < 20; ++q) gv[q] = gp[(size_t)(T_ - 1) * 400 + lane * 20 + q];
      #pragma unroll
      for (int q = 0; q < 20; ++q) gn1[q] = gp[(size_t)(T_ - 2) * 400 + lane * 20 + q];
    }
    for (int t = T_ - 2; t >= 0; --t) {
      if (t >= 2 && lane < C_) {
        #pragma unroll
        for (int q = 0; q < 20; ++q) gn2[q] = gp[(size_t)(t - 1) * 400 + lane * 20 + q];
      }
      float w = ((lane < C_) ? fp[(t + 1) * C_ + lane] : 0.f) + bv;
      float m = -3.0e38f;
      #pragma unroll
      for (int q = 0; q < 20; ++q) {
        float s = gv[q] + __shfl(w, q);
        sv[q] = s; m = fmaxf(m, s);
      }
      float sum = 0.f;
      #pragma unroll
      for (int q = 0; q < 20; ++q) sum += __expf(sv[q] - m);
      bv = m + __logf(sum);
      if (lane < C_) bp[(size_t)t * C_ + lane] = bv;
      #pragma unroll
      for (int q = 0; q < 20; ++q) { gv[q] = gn1[q]; gn1[q] = gn2[q]; }
    }
  }
}

// ---------------- logZ per batch ----------------
__global__ void logz_k(const float* __restrict__ alpha, float* __restrict__ lz) {
  int b = blockIdx.x; int lane = threadIdx.x;
  float a = (lane < C_) ? alpha[((size_t)b * T_ + (T_ - 1)) * C_ + lane] : -3.0e38f;
  float m = a;
  #pragma unroll
  for (int o = 32; o > 0; o >>= 1) m = fmaxf(m, __shfl_xor(m, o));
  float e = (lane < C_) ? __expf(a - m) : 0.f;
  #pragma unroll
  for (int o = 32; o > 0; o >>= 1) e += __shfl_xor(e, o);
  if (lane == 0) lz[b] = m + __logf(e);
}

// ---------------- marginals = exp(alpha+beta-logZ) ----------------
__global__ void marg_k(const float* __restrict__ alpha, const float* __restrict__ beta,
                       const float* __restrict__ lz, float* __restrict__ out0) {
  size_t idx = (size_t)blockIdx.x * 256 + threadIdx.x;
  int b = (int)(idx / (T_ * C_));
  out0[idx] = __expf(alpha[idx] + beta[idx] - lz[b]);
}

extern "C" void kernel_launch(void* const* d_in, const int* in_sizes, int n_in,
                              void* d_out, int out_size, void* d_ws, size_t ws_size,
                              hipStream_t stream) {
  const int*   tok   = (const int*)d_in[0];
  const int*   seq   = (const int*)d_in[1];
  const float* emb   = (const float*)d_in[2];
  const float* Wih0  = (const float*)d_in[3];
  const float* Whh0  = (const float*)d_in[4];
  const float* bih0  = (const float*)d_in[5];
  const float* bhh0  = (const float*)d_in[6];
  const float* Wih0r = (const float*)d_in[7];
  const float* Whh0r = (const float*)d_in[8];
  const float* bih0r = (const float*)d_in[9];
  const float* bhh0r = (const float*)d_in[10];
  const float* Wih1  = (const float*)d_in[11];
  const float* Whh1  = (const float*)d_in[12];
  const float* bih1  = (const float*)d_in[13];
  const float* bhh1  = (const float*)d_in[14];
  const float* Wih1r = (const float*)d_in[15];
  const float* Whh1r = (const float*)d_in[16];
  const float* bih1r = (const float*)d_in[17];
  const float* bhh1r = (const float*)d_in[18];
  const float* fW    = (const float*)d_in[19];
  const float* fb    = (const float*)d_in[20];
  const float* gW    = (const float*)d_in[21];
  const float* gb    = (const float*)d_in[22];
  const float* h0    = (const float*)d_in[23];
  const float* c0    = (const float*)d_in[24];

  float* ws = (float*)d_ws;
  float* x0 = ws;                         // 4,194,304 floats
  float* xp = ws + 4194304;               // 2*B*T*400 = 104,857,600 floats
  float* x1 = ws + 109051904;             // 26,214,400 floats (layer0 out; reused as layer1 out)
  float* lz = ws + 135266304;             // 128 floats

  float* out   = (float*)d_out;
  float* f_out = out + 2621440;
  float* g_out = out + 5242880;
  float* a_out = out + 57671680;
  float* b_out = out + 60293120;

  embed_k<<<16384, 256, 0, stream>>>(tok, emb, x0);

  dim3 g400(2048, 7), g20(2048, 1);
  // layer 0 input projections (K=32)
  gemm_nt<<<g400, 256, 0, stream>>>(x0, Wih0,  bih0,  bhh0,  xp,                    32, 400, 400);
  gemm_nt<<<g400, 256, 0, stream>>>(x0, Wih0r, bih0r, bhh0r, xp + (size_t)52428800, 32, 400, 400);
  lstm_scan<<<256, 1024, 0, stream>>>(xp, Whh0, Whh0r, h0, c0, nullptr, x1, 0);
  // layer 1 input projections (K=200)
  gemm_nt<<<g400, 256, 0, stream>>>(x1, Wih1,  bih1,  bhh1,  xp,                    200, 400, 400);
  gemm_nt<<<g400, 256, 0, stream>>>(x1, Wih1r, bih1r, bhh1r, xp + (size_t)52428800, 200, 400, 400);
  lstm_scan<<<256, 1024, 0, stream>>>(xp, Whh1, Whh1r, h0, c0, seq, x1, 1);  // x1 reused as h
  // emissions + transitions
  gemm_nt<<<g20,  256, 0, stream>>>(x1, fW, fb, nullptr, f_out, 200, 20,  20);
  gemm_nt<<<g400, 256, 0, stream>>>(x1, gW, gb, nullptr, g_out, 200, 400, 400);
  // CRF forward/backward (alpha: blocks 0..127, beta: 128..255)
  crf_k<<<256, 64, 0, stream>>>(f_out, g_out, a_out, b_out);
  logz_k<<<128, 64, 0, stream>>>(a_out, lz);
  marg_k<<<10240, 256, 0, stream>>>(a_out, b_out, lz, out);
}

// Round 4
// 4203.705 us; speedup vs baseline: 1.3192x; 1.0586x over previous
//
#include <hip/hip_runtime.h>
#include <hip/hip_bf16.h>

#define B_ 128
#define T_ 1024
#define E_ 32
#define H_ 100
#define C_ 20
#define M_ (B_*T_)   // 131072

// ---------------- embedding lookup ----------------
__global__ void embed_k(const int* __restrict__ tok, const float* __restrict__ emb,
                        float* __restrict__ x0) {
  int idx = blockIdx.x * 256 + threadIdx.x;   // over M_*E_ = 4194304
  int bt = idx >> 5;
  int e  = idx & 31;
  x0[idx] = emb[tok[bt] * E_ + e];
}

// ---------------- generic fp32 GEMM: C[M,N] = A[M,K] @ W[N,K]^T + b1 + b2 ----
// BM=64, BN=64, BK=8, 256 threads, 4x4 microtile
__global__ __launch_bounds__(256) void gemm_nt(
    const float* __restrict__ A, const float* __restrict__ W,
    const float* __restrict__ b1, const float* __restrict__ b2,
    float* __restrict__ C, int K, int N, int ldc)
{
  const int BK = 8;
  __shared__ __align__(16) float As[BK][68];
  __shared__ __align__(16) float Ws[BK][68];
  int tid = threadIdx.x;
  size_t m0 = (size_t)blockIdx.x * 64;
  int n0 = blockIdx.y * 64;
  int ty = tid >> 4, tx = tid & 15;
  int lm = tid >> 2;          // 0..63
  int lk = (tid & 3) * 2;     // 0,2,4,6
  float acc[4][4] = {{0.f}};
  const float* Ap = A + (m0 + (size_t)lm) * K + lk;
  bool wok = (n0 + lm) < N;
  const float* Wp = wok ? (W + (size_t)(n0 + lm) * K + lk) : W;
  for (int k0 = 0; k0 < K; k0 += BK) {
    float2 av = *(const float2*)(Ap + k0);
    float2 wv = wok ? *(const float2*)(Wp + k0) : make_float2(0.f, 0.f);
    As[lk][lm] = av.x; As[lk + 1][lm] = av.y;
    Ws[lk][lm] = wv.x; Ws[lk + 1][lm] = wv.y;
    __syncthreads();
    #pragma unroll
    for (int k = 0; k < BK; ++k) {
      float4 a4 = *(const float4*)&As[k][ty * 4];
      float4 w4 = *(const float4*)&Ws[k][tx * 4];
      float ar[4] = {a4.x, a4.y, a4.z, a4.w};
      float wr[4] = {w4.x, w4.y, w4.z, w4.w};
      #pragma unroll
      for (int i = 0; i < 4; ++i)
        #pragma unroll
        for (int j = 0; j < 4; ++j)
          acc[i][j] = fmaf(ar[i], wr[j], acc[i][j]);
    }
    __syncthreads();
  }
  #pragma unroll
  for (int i = 0; i < 4; ++i) {
    size_t row = m0 + ty * 4 + i;
    #pragma unroll
    for (int j = 0; j < 4; ++j) {
      int col = n0 + tx * 4 + j;
      if (col < N) {
        float bv = (b1 ? b1[col] : 0.f) + (b2 ? b2[col] : 0.f);
        C[row * (size_t)ldc + col] = acc[i][j] + bv;
      }
    }
  }
}

// Pin a float4's components into VGPRs: the empty asm redefines the SSA
// values, so LLVM can no longer rematerialize the (invariant) load that
// produced them and must keep them register-resident across the scan loop.
// Rounds 1-3 evidence: without this, allocator reports 56-120 VGPR (below
// static demand) and re-fetches W_hh from L2 every timestep (~43 GB -> ~1.1ms).
#define PIN4(v) asm volatile("" : "+v"((v).x), "+v"((v).y), "+v"((v).z), "+v"((v).w))

// ---------------- LSTM scan (one WG per (batch, direction)) -----------------
// xp: [2][B][T][400] precomputed input projections (+both biases)
// 1024 threads: thread pair (2r, 2r+1) owns W_hh row r split 52/48 along k.
// Per-thread weight footprint = 13 float4 = 52 VGPR, pinned via PIN4.
__global__
__attribute__((amdgpu_flat_work_group_size(1024, 1024), amdgpu_waves_per_eu(4, 4)))
void lstm_scan(
    const float* __restrict__ xp,
    const float* __restrict__ WhhF, const float* __restrict__ WhhR,
    const float* __restrict__ h0, const float* __restrict__ c0, // [4][B][H]
    const int* __restrict__ seqlen,   // null => no mask
    float* __restrict__ outbuf,       // [B][T][200], dir*100 offset
    int layer)
{
  int wg = blockIdx.x; int dir = wg & 1; int b = wg >> 1;
  int tid = threadIdx.x;
  const float* Whh = dir ? WhhR : WhhF;
  const float* xpp = xp + ((size_t)dir * B_ + b) * T_ * 400;
  const float* h0p = h0 + ((size_t)(2 * layer + dir) * B_ + b) * H_;
  const float* c0p = c0 + ((size_t)(2 * layer + dir) * B_ + b) * H_;
  __shared__ __align__(16) float hsh[104];
  __shared__ __align__(16) float gsh[400];
  int r = tid >> 1;          // gate row 0..511 (active < 400)
  int half = tid & 1;        // k-half: 0 -> [0,52), 1 -> [52,100)
  bool act = (tid < 800);
  int kbase = half ? 52 : 0;
  float4 w[13];
  if (act) {
    const float4* p = (const float4*)(Whh + (size_t)r * H_ + kbase);
    #pragma unroll
    for (int j = 0; j < 12; ++j) w[j] = p[j];
    w[12] = half ? make_float4(0.f, 0.f, 0.f, 0.f) : p[12];
    #pragma unroll
    for (int j = 0; j < 13; ++j) PIN4(w[j]);
  }
  if (tid < H_) hsh[tid] = h0p[tid];
  float c = (tid < H_) ? c0p[tid] : 0.f;
  int sl = seqlen ? seqlen[b] : T_;
  __syncthreads();
  int tstep = dir ? -1 : 1;
  int t0 = dir ? (T_ - 1) : 0;
  float xc = 0.f, xn = 0.f;
  if (act) {
    xc = xpp[(size_t)t0 * 400 + r];
    xn = xpp[(size_t)(t0 + tstep) * 400 + r];
  }
  for (int tt = 0; tt < T_; ++tt) {
    int t = t0 + tstep * tt;
    float xn2 = 0.f;
    if (act && tt + 2 < T_)
      xn2 = xpp[(size_t)(t + 2 * tstep) * 400 + r];
    if (act) {
      // two independent chains to hide FMA latency
      float s0 = half ? 0.f : xc;
      float s1 = 0.f;
      #pragma unroll
      for (int j = 0; j < 13; j += 2) {
        float4 hv = *(const float4*)&hsh[kbase + 4 * j];
        s0 = fmaf(w[j].x, hv.x, s0); s0 = fmaf(w[j].y, hv.y, s0);
        s0 = fmaf(w[j].z, hv.z, s0); s0 = fmaf(w[j].w, hv.w, s0);
      }
      #pragma unroll
      for (int j = 1; j < 13; j += 2) {
        float4 hv = *(const float4*)&hsh[kbase + 4 * j];
        s1 = fmaf(w[j].x, hv.x, s1); s1 = fmaf(w[j].y, hv.y, s1);
        s1 = fmaf(w[j].z, hv.z, s1); s1 = fmaf(w[j].w, hv.w, s1);
      }
      float s = s0 + s1;
      s += __shfl_xor(s, 1);   // combine the two k-halves (adjacent lanes)
      if (!half) gsh[r] = s;
    }
    __syncthreads();
    if (tid < H_) {
      float gi = gsh[tid], gf = gsh[H_ + tid], gg = gsh[2 * H_ + tid], go = gsh[3 * H_ + tid];
      float si = 1.f / (1.f + __expf(-gi));
      float sf = 1.f / (1.f + __expf(-gf));
      float so = 1.f / (1.f + __expf(-go));
      float tg = 1.f - 2.f / (1.f + __expf(2.f * gg));
      c = fmaf(sf, c, si * tg);
      float tc = 1.f - 2.f / (1.f + __expf(2.f * c));
      float h = so * tc;
      hsh[tid] = h;
      outbuf[((size_t)b * T_ + t) * 200 + dir * H_ + tid] = (t < sl) ? h : 0.f;
    }
    __syncthreads();
    xc = xn; xn = xn2;
  }
}

// ---------------- CRF alpha (wg<B) + beta (wg>=B), one wave per batch -------
__global__ __launch_bounds__(64) void crf_k(
    const float* __restrict__ f, const float* __restrict__ g,
    float* __restrict__ alpha, float* __restrict__ beta)
{
  int wg = blockIdx.x;
  int lane = threadIdx.x;
  float gv[20], gn1[20], gn2[20], sv[20];
  #pragma unroll
  for (int q = 0; q < 20; ++q) { gv[q] = 0.f; gn1[q] = 0.f; gn2[q] = 0.f; }
  if (wg < B_) {
    int b = wg;
    const float* fp = f + (size_t)b * T_ * C_;
    const float* gp = g + (size_t)b * T_ * C_ * C_;
    float* ap = alpha + (size_t)b * T_ * C_;
    float a = 0.f;
    if (lane < C_) { a = fp[lane]; ap[lane] = a; }
    if (lane < C_) {
      #pragma unroll
      for (int q = 0; q < 20; ++q) gv[q] = gp[(size_t)1 * 400 + q * 20 + lane];
      #pragma unroll
      for (int q = 0; q < 20; ++q) gn1[q] = gp[(size_t)2 * 400 + q * 20 + lane];
    }
    for (int t = 1; t < T_; ++t) {
      if (t + 2 < T_ && lane < C_) {
        #pragma unroll
        for (int q = 0; q < 20; ++q) gn2[q] = gp[(size_t)(t + 2) * 400 + q * 20 + lane];
      }
      float ft = (lane < C_) ? fp[t * C_ + lane] : 0.f;
      float m = -3.0e38f;
      #pragma unroll
      for (int q = 0; q < 20; ++q) {
        float s = __shfl(a, q) + gv[q];
        sv[q] = s; m = fmaxf(m, s);
      }
      float sum = 0.f;
      #pragma unroll
      for (int q = 0; q < 20; ++q) sum += __expf(sv[q] - m);
      a = ft + m + __logf(sum);
      if (lane < C_) ap[(size_t)t * C_ + lane] = a;
      #pragma unroll
      for (int q = 0; q < 20; ++q) { gv[q] = gn1[q]; gn1[q] = gn2[q]; }
    }
  } else {
    int b = wg - B_;
    const float* fp = f + (size_t)b * T_ * C_;
    const float* gp = g + (size_t)b * T_ * C_ * C_;
    float* bp = beta + (size_t)b * T_ * C_;
    float bv = 0.f;
    if (lane < C_) bp[(size_t)(T_ - 1) * C_ + lane] = 0.f;
    if (lane < C_) {
      #pragma unroll
      for (int q = 0; q < 20; ++q) gv[q] = gp[(size_t)(T_ - 1) * 400 + lane * 20 + q];
      #pragma unroll
      for (int q = 0; q < 20; ++q) gn1[q] = gp[(size_t)(T_ - 2) * 400 + lane * 20 + q];
    }
    for (int t = T_ - 2; t >= 0; --t) {
      if (t >= 2 && lane < C_) {
        #pragma unroll
        for (int q = 0; q < 20; ++q) gn2[q] = gp[(size_t)(t - 1) * 400 + lane * 20 + q];
      }
      float w = ((lane < C_) ? fp[(t + 1) * C_ + lane] : 0.f) + bv;
      float m = -3.0e38f;
      #pragma unroll
      for (int q = 0; q < 20; ++q) {
        float s = gv[q] + __shfl(w, q);
        sv[q] = s; m = fmaxf(m, s);
      }
      float sum = 0.f;
      #pragma unroll
      for (int q = 0; q < 20; ++q) sum += __expf(sv[q] - m);
      bv = m + __logf(sum);
      if (lane < C_) bp[(size_t)t * C_ + lane] = bv;
      #pragma unroll
      for (int q = 0; q < 20; ++q) { gv[q] = gn1[q]; gn1[q] = gn2[q]; }
    }
  }
}

// ---------------- logZ per batch ----------------
__global__ void logz_k(const float* __restrict__ alpha, float* __restrict__ lz) {
  int b = blockIdx.x; int lane = threadIdx.x;
  float a = (lane < C_) ? alpha[((size_t)b * T_ + (T_ - 1)) * C_ + lane] : -3.0e38f;
  float m = a;
  #pragma unroll
  for (int o = 32; o > 0; o >>= 1) m = fmaxf(m, __shfl_xor(m, o));
  float e = (lane < C_) ? __expf(a - m) : 0.f;
  #pragma unroll
  for (int o = 32; o > 0; o >>= 1) e += __shfl_xor(e, o);
  if (lane == 0) lz[b] = m + __logf(e);
}

// ---------------- marginals = exp(alpha+beta-logZ) ----------------
__global__ void marg_k(const float* __restrict__ alpha, const float* __restrict__ beta,
                       const float* __restrict__ lz, float* __restrict__ out0) {
  size_t idx = (size_t)blockIdx.x * 256 + threadIdx.x;
  int b = (int)(idx / (T_ * C_));
  out0[idx] = __expf(alpha[idx] + beta[idx] - lz[b]);
}

extern "C" void kernel_launch(void* const* d_in, const int* in_sizes, int n_in,
                              void* d_out, int out_size, void* d_ws, size_t ws_size,
                              hipStream_t stream) {
  const int*   tok   = (const int*)d_in[0];
  const int*   seq   = (const int*)d_in[1];
  const float* emb   = (const float*)d_in[2];
  const float* Wih0  = (const float*)d_in[3];
  const float* Whh0  = (const float*)d_in[4];
  const float* bih0  = (const float*)d_in[5];
  const float* bhh0  = (const float*)d_in[6];
  const float* Wih0r = (const float*)d_in[7];
  const float* Whh0r = (const float*)d_in[8];
  const float* bih0r = (const float*)d_in[9];
  const float* bhh0r = (const float*)d_in[10];
  const float* Wih1  = (const float*)d_in[11];
  const float* Whh1  = (const float*)d_in[12];
  const float* bih1  = (const float*)d_in[13];
  const float* bhh1  = (const float*)d_in[14];
  const float* Wih1r = (const float*)d_in[15];
  const float* Whh1r = (const float*)d_in[16];
  const float* bih1r = (const float*)d_in[17];
  const float* bhh1r = (const float*)d_in[18];
  const float* fW    = (const float*)d_in[19];
  const float* fb    = (const float*)d_in[20];
  const float* gW    = (const float*)d_in[21];
  const float* gb    = (const float*)d_in[22];
  const float* h0    = (const float*)d_in[23];
  const float* c0    = (const float*)d_in[24];

  float* ws = (float*)d_ws;
  float* x0 = ws;                         // 4,194,304 floats
  float* xp = ws + 4194304;               // 2*B*T*400 = 104,857,600 floats
  float* x1 = ws + 109051904;             // 26,214,400 floats (layer0 out; reused as layer1 out)
  float* lz = ws + 135266304;             // 128 floats

  float* out   = (float*)d_out;
  float* f_out = out + 2621440;
  float* g_out = out + 5242880;
  float* a_out = out + 57671680;
  float* b_out = out + 60293120;

  embed_k<<<16384, 256, 0, stream>>>(tok, emb, x0);

  dim3 g400(2048, 7), g20(2048, 1);
  // layer 0 input projections (K=32)
  gemm_nt<<<g400, 256, 0, stream>>>(x0, Wih0,  bih0,  bhh0,  xp,                    32, 400, 400);
  gemm_nt<<<g400, 256, 0, stream>>>(x0, Wih0r, bih0r, bhh0r, xp + (size_t)52428800, 32, 400, 400);
  lstm_scan<<<256, 1024, 0, stream>>>(xp, Whh0, Whh0r, h0, c0, nullptr, x1, 0);
  // layer 1 input projections (K=200)
  gemm_nt<<<g400, 256, 0, stream>>>(x1, Wih1,  bih1,  bhh1,  xp,                    200, 400, 400);
  gemm_nt<<<g400, 256, 0, stream>>>(x1, Wih1r, bih1r, bhh1r, xp + (size_t)52428800, 200, 400, 400);
  lstm_scan<<<256, 1024, 0, stream>>>(xp, Whh1, Whh1r, h0, c0, seq, x1, 1);  // x1 reused as h
  // emissions + transitions
  gemm_nt<<<g20,  256, 0, stream>>>(x1, fW, fb, nullptr, f_out, 200, 20,  20);
  gemm_nt<<<g400, 256, 0, stream>>>(x1, gW, gb, nullptr, g_out, 200, 400, 400);
  // CRF forward/backward (alpha: blocks 0..127, beta: 128..255)
  crf_k<<<256, 64, 0, stream>>>(f_out, g_out, a_out, b_out);
  logz_k<<<128, 64, 0, stream>>>(a_out, lz);
  marg_k<<<10240, 256, 0, stream>>>(a_out, b_out, lz, out);
}

// Round 5
// 4129.321 us; speedup vs baseline: 1.3429x; 1.0180x over previous
//
#include <hip/hip_runtime.h>
#include <hip/hip_bf16.h>

#define B_ 128
#define T_ 1024
#define E_ 32
#define H_ 100
#define C_ 20
#define M_ (B_*T_)   // 131072

// ---------------- embedding lookup ----------------
__global__ void embed_k(const int* __restrict__ tok, const float* __restrict__ emb,
                        float* __restrict__ x0) {
  int idx = blockIdx.x * 256 + threadIdx.x;   // over M_*E_ = 4194304
  int bt = idx >> 5;
  int e  = idx & 31;
  x0[idx] = emb[tok[bt] * E_ + e];
}

// ---------------- generic fp32 GEMM: C[M,N] = A[M,K] @ W[N,K]^T + b1 + b2 ----
// BM=64, BN=64, BK=8, 256 threads, 4x4 microtile
__global__ __launch_bounds__(256) void gemm_nt(
    const float* __restrict__ A, const float* __restrict__ W,
    const float* __restrict__ b1, const float* __restrict__ b2,
    float* __restrict__ C, int K, int N, int ldc)
{
  const int BK = 8;
  __shared__ __align__(16) float As[BK][68];
  __shared__ __align__(16) float Ws[BK][68];
  int tid = threadIdx.x;
  size_t m0 = (size_t)blockIdx.x * 64;
  int n0 = blockIdx.y * 64;
  int ty = tid >> 4, tx = tid & 15;
  int lm = tid >> 2;          // 0..63
  int lk = (tid & 3) * 2;     // 0,2,4,6
  float acc[4][4] = {{0.f}};
  const float* Ap = A + (m0 + (size_t)lm) * K + lk;
  bool wok = (n0 + lm) < N;
  const float* Wp = wok ? (W + (size_t)(n0 + lm) * K + lk) : W;
  for (int k0 = 0; k0 < K; k0 += BK) {
    float2 av = *(const float2*)(Ap + k0);
    float2 wv = wok ? *(const float2*)(Wp + k0) : make_float2(0.f, 0.f);
    As[lk][lm] = av.x; As[lk + 1][lm] = av.y;
    Ws[lk][lm] = wv.x; Ws[lk + 1][lm] = wv.y;
    __syncthreads();
    #pragma unroll
    for (int k = 0; k < BK; ++k) {
      float4 a4 = *(const float4*)&As[k][ty * 4];
      float4 w4 = *(const float4*)&Ws[k][tx * 4];
      float ar[4] = {a4.x, a4.y, a4.z, a4.w};
      float wr[4] = {w4.x, w4.y, w4.z, w4.w};
      #pragma unroll
      for (int i = 0; i < 4; ++i)
        #pragma unroll
        for (int j = 0; j < 4; ++j)
          acc[i][j] = fmaf(ar[i], wr[j], acc[i][j]);
    }
    __syncthreads();
  }
  #pragma unroll
  for (int i = 0; i < 4; ++i) {
    size_t row = m0 + ty * 4 + i;
    #pragma unroll
    for (int j = 0; j < 4; ++j) {
      int col = n0 + tx * 4 + j;
      if (col < N) {
        float bv = (b1 ? b1[col] : 0.f) + (b2 ? b2[col] : 0.f);
        C[row * (size_t)ldc + col] = acc[i][j] + bv;
      }
    }
  }
}

// Pin a float4's components into VGPRs (blocks rematerialization of the load).
#define PIN4(v) asm volatile("" : "+v"((v).x), "+v"((v).y), "+v"((v).z), "+v"((v).w))

// ---------------- LSTM scan (one WG per (batch, direction)) -----------------
// 256 threads; thread tid<200 owns FULL gate rows 2tid and 2tid+1 of W_hh
// (50 float4 = 200 VGPRs, pinned). h is distributed via v_readlane (lane<25
// stages h as one exec-masked b128 read; 100 readlanes/wave feed the FMA's
// scalar operand) -- no LDS broadcast fan-out (64-lane fanout has NO
// broadcast discount: ~1600cy/step in rounds 1-4).
// ~64KB static LDS caps compiler occupancy at 2 WG/CU -> 256-VGPR budget ->
// allocator has no occupancy incentive to remat/spill the weights (rounds
// 1-4: allocator targeted ~8 waves/EU and spilled/remat'd at 56-120 VGPRs).
// +24KB dynamic LDS at launch caps runtime at 1 WG/CU (spread over 256 CUs).
__global__ __launch_bounds__(256, 2) void lstm_scan(
    const float* __restrict__ xp,
    const float* __restrict__ WhhF, const float* __restrict__ WhhR,
    const float* __restrict__ h0, const float* __restrict__ c0, // [4][B][H]
    const int* __restrict__ seqlen,   // null => no mask
    float* __restrict__ outbuf,       // [B][T][200], dir*100 offset
    int layer)
{
  int wg = blockIdx.x; int dir = wg & 1; int b = wg >> 1;
  int tid = threadIdx.x;
  int lane = tid & 63;
  const float* Whh = dir ? WhhR : WhhF;
  const float* xpp = xp + ((size_t)dir * B_ + b) * T_ * 400;
  const float* h0p = h0 + ((size_t)(2 * layer + dir) * B_ + b) * H_;
  const float* c0p = c0 + ((size_t)(2 * layer + dir) * B_ + b) * H_;
  __shared__ __align__(16) float hsh[104];
  __shared__ __align__(16) float gsh[400];
  __shared__ float deadpad[15744];   // occupancy cap: total static LDS ~64KB
  if (seqlen == (const int*)0x1) deadpad[tid] = 1.f;  // keep deadpad alive
  bool act = (tid < 200);
  float4 w0[25], w1[25];
  if (act) {
    const float4* p0 = (const float4*)(Whh + (size_t)(2 * tid) * H_);
    const float4* p1 = (const float4*)(Whh + (size_t)(2 * tid + 1) * H_);
    #pragma unroll
    for (int j = 0; j < 25; ++j) { w0[j] = p0[j]; w1[j] = p1[j]; }
    #pragma unroll
    for (int j = 0; j < 25; ++j) { PIN4(w0[j]); PIN4(w1[j]); }
  }
  if (tid < H_) hsh[tid] = h0p[tid];
  float c = (tid < H_) ? c0p[tid] : 0.f;
  int sl = seqlen ? seqlen[b] : T_;
  __syncthreads();
  int tstep = dir ? -1 : 1;
  int t0 = dir ? (T_ - 1) : 0;
  float2 xc = make_float2(0.f, 0.f), xn = make_float2(0.f, 0.f);
  if (act) {
    xc = *(const float2*)(xpp + (size_t)t0 * 400 + 2 * tid);
    xn = *(const float2*)(xpp + (size_t)(t0 + tstep) * 400 + 2 * tid);
  }
  for (int tt = 0; tt < T_; ++tt) {
    int t = t0 + tstep * tt;
    float2 xn2 = make_float2(0.f, 0.f);
    if (act && tt + 2 < T_)
      xn2 = *(const float2*)(xpp + (size_t)(t + 2 * tstep) * 400 + 2 * tid);
    // stage h into lanes 0..24 of every wave (tiny exec-masked fanout)
    float4 h4;
    if (lane < 25) h4 = ((const float4*)hsh)[lane];
    if (act) {
      float a0 = xc.x, a1 = xc.y;
      #pragma unroll
      for (int j = 0; j < 25; ++j) {
        float b0 = __uint_as_float(__builtin_amdgcn_readlane(__float_as_uint(h4.x), j));
        float b1 = __uint_as_float(__builtin_amdgcn_readlane(__float_as_uint(h4.y), j));
        float b2 = __uint_as_float(__builtin_amdgcn_readlane(__float_as_uint(h4.z), j));
        float b3 = __uint_as_float(__builtin_amdgcn_readlane(__float_as_uint(h4.w), j));
        a0 = fmaf(w0[j].x, b0, a0); a1 = fmaf(w1[j].x, b0, a1);
        a0 = fmaf(w0[j].y, b1, a0); a1 = fmaf(w1[j].y, b1, a1);
        a0 = fmaf(w0[j].z, b2, a0); a1 = fmaf(w1[j].z, b2, a1);
        a0 = fmaf(w0[j].w, b3, a0); a1 = fmaf(w1[j].w, b3, a1);
      }
      *(float2*)&gsh[2 * tid] = make_float2(a0, a1);
    }
    __syncthreads();
    if (tid < H_) {
      float gi = gsh[tid], gf = gsh[H_ + tid], gg = gsh[2 * H_ + tid], go = gsh[3 * H_ + tid];
      float si = 1.f / (1.f + __expf(-gi));
      float sf = 1.f / (1.f + __expf(-gf));
      float so = 1.f / (1.f + __expf(-go));
      float tg = 1.f - 2.f / (1.f + __expf(2.f * gg));
      c = fmaf(sf, c, si * tg);
      float tc = 1.f - 2.f / (1.f + __expf(2.f * c));
      float h = so * tc;
      hsh[tid] = h;
      outbuf[((size_t)b * T_ + t) * 200 + dir * H_ + tid] = (t < sl) ? h : 0.f;
    }
    __syncthreads();
    xc = xn; xn = xn2;
  }
}

// ---------------- CRF alpha (wg<B) + beta (wg>=B), one wave per batch -------
__global__ __launch_bounds__(64) void crf_k(
    const float* __restrict__ f, const float* __restrict__ g,
    float* __restrict__ alpha, float* __restrict__ beta)
{
  int wg = blockIdx.x;
  int lane = threadIdx.x;
  float gv[20], gn1[20], gn2[20], sv[20];
  #pragma unroll
  for (int q = 0; q < 20; ++q) { gv[q] = 0.f; gn1[q] = 0.f; gn2[q] = 0.f; }
  if (wg < B_) {
    int b = wg;
    const float* fp = f + (size_t)b * T_ * C_;
    const float* gp = g + (size_t)b * T_ * C_ * C_;
    float* ap = alpha + (size_t)b * T_ * C_;
    float a = 0.f;
    if (lane < C_) { a = fp[lane]; ap[lane] = a; }
    if (lane < C_) {
      #pragma unroll
      for (int q = 0; q < 20; ++q) gv[q] = gp[(size_t)1 * 400 + q * 20 + lane];
      #pragma unroll
      for (int q = 0; q < 20; ++q) gn1[q] = gp[(size_t)2 * 400 + q * 20 + lane];
    }
    for (int t = 1; t < T_; ++t) {
      if (t + 2 < T_ && lane < C_) {
        #pragma unroll
        for (int q = 0; q < 20; ++q) gn2[q] = gp[(size_t)(t + 2) * 400 + q * 20 + lane];
      }
      float ft = (lane < C_) ? fp[t * C_ + lane] : 0.f;
      float m = -3.0e38f;
      #pragma unroll
      for (int q = 0; q < 20; ++q) {
        float s = __shfl(a, q) + gv[q];
        sv[q] = s; m = fmaxf(m, s);
      }
      float sum = 0.f;
      #pragma unroll
      for (int q = 0; q < 20; ++q) sum += __expf(sv[q] - m);
      a = ft + m + __logf(sum);
      if (lane < C_) ap[(size_t)t * C_ + lane] = a;
      #pragma unroll
      for (int q = 0; q < 20; ++q) { gv[q] = gn1[q]; gn1[q] = gn2[q]; }
    }
  } else {
    int b = wg - B_;
    const float* fp = f + (size_t)b * T_ * C_;
    const float* gp = g + (size_t)b * T_ * C_ * C_;
    float* bp = beta + (size_t)b * T_ * C_;
    float bv = 0.f;
    if (lane < C_) bp[(size_t)(T_ - 1) * C_ + lane] = 0.f;
    if (lane < C_) {
      #pragma unroll
      for (int q = 0; q < 20; ++q) gv[q] = gp[(size_t)(T_ - 1) * 400 + lane * 20 + q];
      #pragma unroll
      for (int q = 0; q < 20; ++q) gn1[q] = gp[(size_t)(T_ - 2) * 400 + lane * 20 + q];
    }
    for (int t = T_ - 2; t >= 0; --t) {
      if (t >= 2 && lane < C_) {
        #pragma unroll
        for (int q = 0; q < 20; ++q) gn2[q] = gp[(size_t)(t - 1) * 400 + lane * 20 + q];
      }
      float w = ((lane < C_) ? fp[(t + 1) * C_ + lane] : 0.f) + bv;
      float m = -3.0e38f;
      #pragma unroll
      for (int q = 0; q < 20; ++q) {
        float s = gv[q] + __shfl(w, q);
        sv[q] = s; m = fmaxf(m, s);
      }
      float sum = 0.f;
      #pragma unroll
      for (int q = 0; q < 20; ++q) sum += __expf(sv[q] - m);
      bv = m + __logf(sum);
      if (lane < C_) bp[(size_t)t * C_ + lane] = bv;
      #pragma unroll
      for (int q = 0; q < 20; ++q) { gv[q] = gn1[q]; gn1[q] = gn2[q]; }
    }
  }
}

// ---------------- logZ per batch ----------------
__global__ void logz_k(const float* __restrict__ alpha, float* __restrict__ lz) {
  int b = blockIdx.x; int lane = threadIdx.x;
  float a = (lane < C_) ? alpha[((size_t)b * T_ + (T_ - 1)) * C_ + lane] : -3.0e38f;
  float m = a;
  #pragma unroll
  for (int o = 32; o > 0; o >>= 1) m = fmaxf(m, __shfl_xor(m, o));
  float e = (lane < C_) ? __expf(a - m) : 0.f;
  #pragma unroll
  for (int o = 32; o > 0; o >>= 1) e += __shfl_xor(e, o);
  if (lane == 0) lz[b] = m + __logf(e);
}

// ---------------- marginals = exp(alpha+beta-logZ) ----------------
__global__ void marg_k(const float* __restrict__ alpha, const float* __restrict__ beta,
                       const float* __restrict__ lz, float* __restrict__ out0) {
  size_t idx = (size_t)blockIdx.x * 256 + threadIdx.x;
  int b = (int)(idx / (T_ * C_));
  out0[idx] = __expf(alpha[idx] + beta[idx] - lz[b]);
}

extern "C" void kernel_launch(void* const* d_in, const int* in_sizes, int n_in,
                              void* d_out, int out_size, void* d_ws, size_t ws_size,
                              hipStream_t stream) {
  const int*   tok   = (const int*)d_in[0];
  const int*   seq   = (const int*)d_in[1];
  const float* emb   = (const float*)d_in[2];
  const float* Wih0  = (const float*)d_in[3];
  const float* Whh0  = (const float*)d_in[4];
  const float* bih0  = (const float*)d_in[5];
  const float* bhh0  = (const float*)d_in[6];
  const float* Wih0r = (const float*)d_in[7];
  const float* Whh0r = (const float*)d_in[8];
  const float* bih0r = (const float*)d_in[9];
  const float* bhh0r = (const float*)d_in[10];
  const float* Wih1  = (const float*)d_in[11];
  const float* Whh1  = (const float*)d_in[12];
  const float* bih1  = (const float*)d_in[13];
  const float* bhh1  = (const float*)d_in[14];
  const float* Wih1r = (const float*)d_in[15];
  const float* Whh1r = (const float*)d_in[16];
  const float* bih1r = (const float*)d_in[17];
  const float* bhh1r = (const float*)d_in[18];
  const float* fW    = (const float*)d_in[19];
  const float* fb    = (const float*)d_in[20];
  const float* gW    = (const float*)d_in[21];
  const float* gb    = (const float*)d_in[22];
  const float* h0    = (const float*)d_in[23];
  const float* c0    = (const float*)d_in[24];

  float* ws = (float*)d_ws;
  float* x0 = ws;                         // 4,194,304 floats
  float* xp = ws + 4194304;               // 2*B*T*400 = 104,857,600 floats
  float* x1 = ws + 109051904;             // 26,214,400 floats (layer0 out; reused as layer1 out)
  float* lz = ws + 135266304;             // 128 floats

  float* out   = (float*)d_out;
  float* f_out = out + 2621440;
  float* g_out = out + 5242880;
  float* a_out = out + 57671680;
  float* b_out = out + 60293120;

  embed_k<<<16384, 256, 0, stream>>>(tok, emb, x0);

  dim3 g400(2048, 7), g20(2048, 1);
  // layer 0 input projections (K=32)
  gemm_nt<<<g400, 256, 0, stream>>>(x0, Wih0,  bih0,  bhh0,  xp,                    32, 400, 400);
  gemm_nt<<<g400, 256, 0, stream>>>(x0, Wih0r, bih0r, bhh0r, xp + (size_t)52428800, 32, 400, 400);
  lstm_scan<<<256, 256, 24576, stream>>>(xp, Whh0, Whh0r, h0, c0, nullptr, x1, 0);
  // layer 1 input projections (K=200)
  gemm_nt<<<g400, 256, 0, stream>>>(x1, Wih1,  bih1,  bhh1,  xp,                    200, 400, 400);
  gemm_nt<<<g400, 256, 0, stream>>>(x1, Wih1r, bih1r, bhh1r, xp + (size_t)52428800, 200, 400, 400);
  lstm_scan<<<256, 256, 24576, stream>>>(xp, Whh1, Whh1r, h0, c0, seq, x1, 1);  // x1 reused as h
  // emissions + transitions
  gemm_nt<<<g20,  256, 0, stream>>>(x1, fW, fb, nullptr, f_out, 200, 20,  20);
  gemm_nt<<<g400, 256, 0, stream>>>(x1, gW, gb, nullptr, g_out, 200, 400, 400);
  // CRF forward/backward (alpha: blocks 0..127, beta: 128..255)
  crf_k<<<256, 64, 0, stream>>>(f_out, g_out, a_out, b_out);
  logz_k<<<128, 64, 0, stream>>>(a_out, lz);
  marg_k<<<10240, 256, 0, stream>>>(a_out, b_out, lz, out);
}